// Round 4
// baseline (665.730 us; speedup 1.0000x reference)
//
#include <hip/hip_runtime.h>

// CRF Viterbi decode: B=256, T=512, K=256, out (B, 514) as int32 tags.
// fwd: one block per batch, 1024 threads = (jp:128 j-pairs) x (g:8 i-groups).
// Thread (jp,g) holds trans[i][2jp..2jp+1] for i in [32g,32g+32) as 32 NAMED
// v2f register variables (guaranteed VGPR residency; round-3's array form
// stayed in scratch -> VGPR_Count=48 and 2.5x VALU overhead).
// Per step: 8 uniform ds_read_b128 state broadcasts, 32 v_pk_add_f32 +
// 32 v_max3_f32 (1 inst/update), 8-way combine via LDS.
// bwd: recompute backpointers via exact f32 equality scan (unchanged).
// ws layout: states[B*T*K] f32 (128 MiB) + transT[K*K] f32 (256 KiB).

#define TK 256
#define TT 512

typedef float v2f __attribute__((ext_vector_type(2)));
typedef float v4f __attribute__((ext_vector_type(4)));

__global__ void transpose_kernel(const float* __restrict__ trans,
                                 float* __restrict__ transT) {
  int j = blockIdx.x;
  int i = threadIdx.x;
  transT[(size_t)j * TK + i] = trans[(size_t)i * TK + j];
}

#define TR_LIST(X) \
  X(0) X(1) X(2) X(3) X(4) X(5) X(6) X(7) X(8) X(9) X(10) X(11) X(12) X(13) \
  X(14) X(15) X(16) X(17) X(18) X(19) X(20) X(21) X(22) X(23) X(24) X(25)   \
  X(26) X(27) X(28) X(29) X(30) X(31)

__global__ __launch_bounds__(1024, 4) void crf_fwd(const float* __restrict__ em,
                                                   const float* __restrict__ trans,
                                                   const int* __restrict__ mask,
                                                   float* __restrict__ states) {
  const int b = blockIdx.x;
  const int tid = threadIdx.x;
  const int jp = tid & 127;  // j-pair: columns {2jp, 2jp+1}
  const int g = tid >> 7;    // i-group: rows [32g, 32g+32); wave-uniform

  __shared__ __align__(16) float st[TK];
  __shared__ v2f part[7][128];
  __shared__ int mk[TT];

  // trans slice as 32 named v2f registers (v2f over the j dimension)
  const float* tb = trans + (size_t)(32 * g) * TK + 2 * jp;
#define TRDECL(n) const v2f t##n = *reinterpret_cast<const v2f*>(tb + (n) * TK);
  TR_LIST(TRDECL)
#undef TRDECL

  if (tid < TT) mk[tid] = mask[(size_t)b * TT + tid];

  const size_t base = (size_t)b * TT * TK;
  v2f cur = {0.f, 0.f};
  if (g == 0) {
    cur = *reinterpret_cast<const v2f*>(em + base + 2 * jp);  // state0
    *reinterpret_cast<v2f*>(st + 2 * jp) = cur;
    *reinterpret_cast<v2f*>(states + base + 2 * jp) = cur;
  }
  __syncthreads();

  const float* stp = st + 32 * g;
  const v2f* emp = reinterpret_cast<const v2f*>(em + base + TK) + jp;  // row 1
  v2f* outp = reinterpret_cast<v2f*>(states + base + TK) + jp;

  v2f enext = {0.f, 0.f};
  if (g == 0) enext = *emp;  // prefetch row t=1

  for (int t = 1; t < TT; ++t) {
    v2f ecur = enext;
    if (g == 0 && t + 1 < TT) enext = *(emp + TK / 2);  // prefetch next row

    float mx = -INFINITY, my = -INFINITY;
    // per 4 i-rows: 4 pk_add + 4 max3 (two accumulator chains)
#define STEP4(k, ta, tb_, tc, td)                                        \
    {                                                                    \
      const v4f s4 = *reinterpret_cast<const v4f*>(stp + 4 * (k));       \
      const v2f a0 = ta + (v2f){s4.x, s4.x};                             \
      const v2f a1 = tb_ + (v2f){s4.y, s4.y};                            \
      const v2f a2 = tc + (v2f){s4.z, s4.z};                             \
      const v2f a3 = td + (v2f){s4.w, s4.w};                             \
      mx = fmaxf(fmaxf(mx, a0.x), a1.x);                                 \
      my = fmaxf(fmaxf(my, a0.y), a1.y);                                 \
      mx = fmaxf(fmaxf(mx, a2.x), a3.x);                                 \
      my = fmaxf(fmaxf(my, a2.y), a3.y);                                 \
    }
    STEP4(0, t0, t1, t2, t3)
    STEP4(1, t4, t5, t6, t7)
    STEP4(2, t8, t9, t10, t11)
    STEP4(3, t12, t13, t14, t15)
    STEP4(4, t16, t17, t18, t19)
    STEP4(5, t20, t21, t22, t23)
    STEP4(6, t24, t25, t26, t27)
    STEP4(7, t28, t29, t30, t31)
#undef STEP4

    if (g) part[g - 1][jp] = (v2f){mx, my};
    __syncthreads();
    if (g == 0) {
#pragma unroll
      for (int p = 0; p < 7; ++p) {
        const v2f q = part[p][jp];
        mx = fmaxf(mx, q.x);
        my = fmaxf(my, q.y);
      }
      const bool vmask = mk[t] > 0;
      v2f nv;
      nv.x = vmask ? mx + ecur.x : cur.x;
      nv.y = vmask ? my + ecur.y : cur.y;
      cur = nv;
      *reinterpret_cast<v2f*>(st + 2 * jp) = nv;
      *outp = nv;
      emp += TK / 2;
      outp += TK / 2;
    }
    __syncthreads();
  }
}

__device__ __forceinline__ float wave_max(float m) {
#pragma unroll
  for (int d = 1; d < 64; d <<= 1) m = fmaxf(m, __shfl_xor(m, d, 64));
  return m;
}

// First index i (lane-major: i = 4*lane + k) whose value equals m.
__device__ __forceinline__ int first_eq_idx(float s0, float s1, float s2,
                                            float s3, float m) {
  unsigned long long b0 = __ballot(s0 == m);
  unsigned long long b1 = __ballot(s1 == m);
  unsigned long long b2 = __ballot(s2 == m);
  unsigned long long b3 = __ballot(s3 == m);
  int best = 0x7fffffff;
  if (b0) best = min(best, 4 * (__ffsll(b0) - 1) + 0);
  if (b1) best = min(best, 4 * (__ffsll(b1) - 1) + 1);
  if (b2) best = min(best, 4 * (__ffsll(b2) - 1) + 2);
  if (b3) best = min(best, 4 * (__ffsll(b3) - 1) + 3);
  return best;
}

// Backward: one wave per batch; 511 serial steps. Recomputes the forward
// argmax exactly (f32 add/max bit-exact; first-occurrence tie-break).
__global__ __launch_bounds__(64, 1) void crf_bwd(const float* __restrict__ states,
                                                 const float* __restrict__ transT,
                                                 const int* __restrict__ mask,
                                                 int* __restrict__ out,
                                                 int out_stride) {
  const int b = blockIdx.x;
  const int lane = threadIdx.x;

  __shared__ int mk[TT];
  for (int q = lane; q < TT; q += 64) mk[q] = mask[(size_t)b * TT + q];
  __syncthreads();

  const size_t sbase = (size_t)b * TT * TK;
  int* outp = out + (size_t)b * out_stride;

  // zero the pad region (harness poisons d_out once)
  for (int q = TT + lane; q < out_stride; q += 64) outp[q] = 0;

  const float* srow = states + sbase;
  float4 r = *reinterpret_cast<const float4*>(srow + (size_t)(TT - 1) * TK + 4 * lane);
  float lm = fmaxf(fmaxf(r.x, r.y), fmaxf(r.z, r.w));
  lm = wave_max(lm);
  int tag = first_eq_idx(r.x, r.y, r.z, r.w, lm);

  auto LOADROW = [&](int rr) -> float4 {
    return *reinterpret_cast<const float4*>(srow + (size_t)rr * TK + 4 * lane);
  };
  float4 p0 = LOADROW(TT - 2), p1 = LOADROW(TT - 3), p2 = LOADROW(TT - 4),
         p3 = LOADROW(TT - 5);

  auto STEP = [&](float4 pr, int t) {
    int mkt = mk[t];
    if (lane == 0) outp[t] = (mkt > 0) ? tag : 0;  // tags * mask
    const float4 tv =
        *reinterpret_cast<const float4*>(transT + (size_t)tag * TK + 4 * lane);
    float s0 = pr.x + tv.x;
    float s1 = pr.y + tv.y;
    float s2 = pr.z + tv.z;
    float s3 = pr.w + tv.w;
    float m = fmaxf(fmaxf(s0, s1), fmaxf(s2, s3));
    m = wave_max(m);
    int prev = first_eq_idx(s0, s1, s2, s3, m);
    tag = (mkt > 0) ? prev : tag;
  };

  int t = TT - 1;
  while (t >= 4) {
    STEP(p0, t);     if (t - 5 >= 0) p0 = LOADROW(t - 5);
    STEP(p1, t - 1); if (t - 6 >= 0) p1 = LOADROW(t - 6);
    STEP(p2, t - 2); if (t - 7 >= 0) p2 = LOADROW(t - 7);
    STEP(p3, t - 3); if (t - 8 >= 0) p3 = LOADROW(t - 8);
    t -= 4;
  }
  STEP(p0, 3);
  STEP(p1, 2);
  STEP(p2, 1);
  if (lane == 0) outp[0] = (mk[0] > 0) ? tag : 0;
}

extern "C" void kernel_launch(void* const* d_in, const int* in_sizes, int n_in,
                              void* d_out, int out_size, void* d_ws, size_t ws_size,
                              hipStream_t stream) {
  const float* em = (const float*)d_in[0];
  const float* trans = (const float*)d_in[1];
  const int* mask = (const int*)d_in[2];
  int* out = (int*)d_out;

  const int B = in_sizes[0] / (TT * TK);      // 256
  const int out_stride = out_size / B;        // 514

  float* states = (float*)d_ws;
  float* transT = states + (size_t)B * TT * TK;

  transpose_kernel<<<TK, TK, 0, stream>>>(trans, transT);
  crf_fwd<<<B, 1024, 0, stream>>>(em, trans, mask, states);
  crf_bwd<<<B, 64, 0, stream>>>(states, transT, mask, out, out_stride);
}